// Round 6
// baseline (390.593 us; speedup 1.0000x reference)
//
#include <hip/hip_runtime.h>
#include <hip/hip_bf16.h>
#include <stdint.h>

// BinaryDiff: out = x @ (base + coeff*(2*mask-1))
// M=8192, K=4096, N=4096. fp32 in/out, bf16 MFMA compute.
// GEMM: 256x256 tile, BK=64, 8 waves (2Mx4N), 4 phases/K-tile, st-swizzled LDS.
// R6: read-ahead pipeline — each phase's fragments are ds_read under the
// PREVIOUS phase's MFMA cluster (bH under Q0, aH under Q1, aL(t+1) under Q3
// after the boundary vmcnt+barrier). Exposed reads/tile: 24 -> 4.

typedef short bf16x8_t __attribute__((ext_vector_type(8)));
typedef float f32x4_t __attribute__((ext_vector_type(4)));
typedef unsigned short u16x8_t __attribute__((ext_vector_type(8)));

#define GLD_LDS16(gptr, lptr)                                                        \
  __builtin_amdgcn_global_load_lds(                                                  \
      (const __attribute__((address_space(1))) void*)(gptr),                         \
      (__attribute__((address_space(3))) void*)(lptr), 16, 0, 0)

#define MFMA_BF16 __builtin_amdgcn_mfma_f32_16x16x32_bf16

// ---------------------------------------------------------------- prep: x -> bf16
__global__ __launch_bounds__(256) void cast_x_kernel(const float* __restrict__ x,
                                                     __hip_bfloat16* __restrict__ xb) {
  size_t i = ((size_t)blockIdx.x * 256 + threadIdx.x) * 8;
  f32x4_t v0 = *(const f32x4_t*)&x[i];
  f32x4_t v1 = *(const f32x4_t*)&x[i + 4];
  __hip_bfloat16 tmp[8];
#pragma unroll
  for (int j = 0; j < 4; ++j) tmp[j] = __float2bfloat16(v0[j]);
#pragma unroll
  for (int j = 0; j < 4; ++j) tmp[4 + j] = __float2bfloat16(v1[j]);
  *(u16x8_t*)&xb[i] = *(const u16x8_t*)tmp;
}

// ------------------------------------- prep: Wt[n][k] = bf16(base[k][n] +/- coeff)
__global__ __launch_bounds__(256) void make_wt_kernel(const float* __restrict__ base,
                                                      const int* __restrict__ mask,
                                                      const float* __restrict__ coeffp,
                                                      __hip_bfloat16* __restrict__ wt,
                                                      int K, int N) {
  __shared__ float tile[32][33];
  const float coeff = coeffp[0];
  const int n0 = blockIdx.x * 32, k0 = blockIdx.y * 32;
  const int tx = threadIdx.x & 31;
  const int ty = threadIdx.x >> 5;
#pragma unroll
  for (int j = 0; j < 4; ++j) {
    int k = k0 + ty + j * 8;
    size_t idx = (size_t)k * N + n0 + tx;
    float b = base[idx];
    int m = mask[idx];
    tile[ty + j * 8][tx] = b + (m ? coeff : -coeff);
  }
  __syncthreads();
#pragma unroll
  for (int j = 0; j < 4; ++j) {
    int n = n0 + ty + j * 8;
    wt[(size_t)n * K + k0 + tx] = __float2bfloat16(tile[tx][ty + j * 8]);
  }
}

// ------------------------------------------------- main GEMM: 256^2 8-phase bf16
// A = xb[M][K], B = wt[N][K] (W^T), C = out[M][N] fp32.
__global__ __launch_bounds__(512, 2) void gemm256_kernel(const __hip_bfloat16* __restrict__ xb,
                                                         const __hip_bfloat16* __restrict__ wt,
                                                         float* __restrict__ out,
                                                         int M, int N, int K) {
  __shared__ __align__(16) __hip_bfloat16 As[2 * 256 * 64];  // 64 KiB (2 x 32 KiB)
  __shared__ __align__(16) __hip_bfloat16 Bs[2 * 256 * 64];  // 64 KiB (2 x 32 KiB)
  const int NT = K >> 6;  // K-tiles of 64

  // XCD-aware swizzle (nwg = 512, %8==0 -> simple bijective form)
  const int nwg = gridDim.x;
  int bid = blockIdx.x;
  int sw = bid;
  if ((nwg & 7) == 0) {
    int per = nwg >> 3;
    sw = (bid & 7) * per + (bid >> 3);
  }
  const int ntn = N >> 8;
  const int tm = sw / ntn, tn = sw - tm * ntn;
  const int m0 = tm << 8, n0 = tn << 8;

  const int tid = threadIdx.x;
  const int lane = tid & 63;
  const int wave = tid >> 6;  // 0..7
  const int wr = wave >> 2;   // 0..1  (M direction, 128 rows each)
  const int wc = wave & 3;    // 0..3  (N direction, 64 cols each)

  // ---- staging: linear LDS dest, pre-swizzled global source (rule #21) ----
  const int lrow = lane >> 3;                 // 0..7 (row within 8-row chunk)
  const int lcol = ((lane & 7) ^ lrow) << 3;  // source col (elems), 16B-slot swizzle
  uint32_t aOff[2][2], bOff[2][2];            // global element offsets (static idx only)
#pragma unroll
  for (int h = 0; h < 2; ++h)
#pragma unroll
    for (int j = 0; j < 2; ++j) {
      aOff[h][j] = (uint32_t)((m0 + h * 128 + wave * 16 + j * 8 + lrow) * K + lcol);
      bOff[h][j] = (uint32_t)((n0 + h * 128 + wave * 16 + j * 8 + lrow) * K + lcol);
    }

// one half-tile = 2 x global_load_lds per wave (8 waves x 2 x 1KiB = 16 KiB)
// buffer half = 256 rows * 128 B = 32768 B -> (tau&1)<<15
#define STAGE_A(h, j, tau)                                                       \
  GLD_LDS16(xb + (size_t)aOff[h][j] + (size_t)(tau) * 64,                        \
            (char*)As + (((tau) & 1) << 15) + ((h) * 16384 + wave * 2048 + (j) * 1024))
#define STAGE_B(h, j, tau)                                                       \
  GLD_LDS16(wt + (size_t)bOff[h][j] + (size_t)(tau) * 64,                        \
            (char*)Bs + (((tau) & 1) << 15) + ((h) * 16384 + wave * 2048 + (j) * 1024))

  // ---- prologue: tile0 all 4 halves + tile1 A0 = 5 halves (10 loads) ----
  STAGE_A(0, 0, 0); STAGE_A(0, 1, 0);
  STAGE_A(1, 0, 0); STAGE_A(1, 1, 0);
  STAGE_B(0, 0, 0); STAGE_B(0, 1, 0);
  STAGE_B(1, 0, 0); STAGE_B(1, 1, 0);
  STAGE_A(0, 0, 1); STAGE_A(0, 1, 1);
  asm volatile("s_waitcnt vmcnt(2)" ::: "memory");  // tile0's 8 loads landed
  __builtin_amdgcn_s_barrier();

  // ---- ds_read addressing: XOR-swizzled (row&7 == lane&7 on fragment rows) ----
  const int lane15 = lane & 15;
  const int swz = (lane & 7) << 4;
  const int c0 = (((lane >> 4) << 4)) ^ swz;      // ks=0 col byte (slots 0..3)
  const int c1 = (64 + ((lane >> 4) << 4)) ^ swz; // ks=1 col byte (slots 4..7)
  const int aRowB = (wr * 128 + lane15) * 128;    // byte row base within buffer
  const int bRowB = (wc * 64 + lane15) * 128;

  f32x4_t acc[8][4];
  const f32x4_t zero = {0.0f, 0.0f, 0.0f, 0.0f};
#pragma unroll
  for (int i = 0; i < 8; ++i)
#pragma unroll
    for (int j = 0; j < 4; ++j) acc[i][j] = zero;

  bf16x8_t aL[4][2], aH[4][2], bL[2][2], bH[2][2];

  // ---- pre-read aL(0) (buf 0; landed per prologue vmcnt+barrier) ----
  {
    const char* a0p = (const char*)As + aRowB;
#pragma unroll
    for (int mi = 0; mi < 4; ++mi) {
      aL[mi][0] = *(const bf16x8_t*)(a0p + mi * 2048 + c0);
      aL[mi][1] = *(const bf16x8_t*)(a0p + mi * 2048 + c1);
    }
  }

  for (int t = 0; t < NT; ++t) {
    const int p = t & 1;
    const char* a0 = (const char*)As + (p << 15) + aRowB;
    const char* b0 = (const char*)Bs + (p << 15) + bRowB;
    const char* a1n = (const char*)As + ((p ^ 1) << 15) + aRowB;  // next tile's A

    // ===== Phase 0: read bL(4, exposed); stage A1(t+1); lgkm0 (aL from P3(t-1)
    //       + bL); issue bH(4) ahead; MFMA Q0 (aL x bL) =====
#pragma unroll
    for (int ni = 0; ni < 2; ++ni) {
      bL[ni][0] = *(const bf16x8_t*)(b0 + ni * 2048 + c0);
      bL[ni][1] = *(const bf16x8_t*)(b0 + ni * 2048 + c1);
    }
    if (t + 1 < NT) { STAGE_A(1, 0, t + 1); STAGE_A(1, 1, t + 1); }
    __builtin_amdgcn_s_barrier();
    asm volatile("s_waitcnt lgkmcnt(0)" ::: "memory");
    __builtin_amdgcn_sched_barrier(0);
#pragma unroll
    for (int ni = 0; ni < 2; ++ni) {  // read-ahead for Q1 (hides under Q0)
      bH[ni][0] = *(const bf16x8_t*)(b0 + (ni + 2) * 2048 + c0);
      bH[ni][1] = *(const bf16x8_t*)(b0 + (ni + 2) * 2048 + c1);
    }
    __builtin_amdgcn_sched_barrier(0);
    __builtin_amdgcn_s_setprio(1);
#pragma unroll
    for (int mi = 0; mi < 4; ++mi)
#pragma unroll
      for (int ni = 0; ni < 2; ++ni) {
        acc[mi][ni] = MFMA_BF16(aL[mi][0], bL[ni][0], acc[mi][ni], 0, 0, 0);
        acc[mi][ni] = MFMA_BF16(aL[mi][1], bL[ni][1], acc[mi][ni], 0, 0, 0);
      }
    __builtin_amdgcn_s_setprio(0);
    __builtin_amdgcn_s_barrier();

    // ===== Phase 1: stage B0(t+1); lgkm0 (bH done); issue aH(8) ahead;
    //       MFMA Q1 (aL x bH) =====
    if (t + 1 < NT) { STAGE_B(0, 0, t + 1); STAGE_B(0, 1, t + 1); }
    __builtin_amdgcn_s_barrier();
    asm volatile("s_waitcnt lgkmcnt(0)" ::: "memory");
    __builtin_amdgcn_sched_barrier(0);
#pragma unroll
    for (int mi = 0; mi < 4; ++mi) {  // read-ahead for Q2 (hides under Q1)
      aH[mi][0] = *(const bf16x8_t*)(a0 + (mi + 4) * 2048 + c0);
      aH[mi][1] = *(const bf16x8_t*)(a0 + (mi + 4) * 2048 + c1);
    }
    __builtin_amdgcn_sched_barrier(0);
    __builtin_amdgcn_s_setprio(1);
#pragma unroll
    for (int mi = 0; mi < 4; ++mi)
#pragma unroll
      for (int ni = 0; ni < 2; ++ni) {
        acc[mi][ni + 2] = MFMA_BF16(aL[mi][0], bH[ni][0], acc[mi][ni + 2], 0, 0, 0);
        acc[mi][ni + 2] = MFMA_BF16(aL[mi][1], bH[ni][1], acc[mi][ni + 2], 0, 0, 0);
      }
    __builtin_amdgcn_s_setprio(0);
    __builtin_amdgcn_s_barrier();

    // ===== Phase 2: stage B1(t+1); lgkm0 (aH done); MFMA Q2 (aH x bH) =====
    if (t + 1 < NT) { STAGE_B(1, 0, t + 1); STAGE_B(1, 1, t + 1); }
    __builtin_amdgcn_s_barrier();
    asm volatile("s_waitcnt lgkmcnt(0)" ::: "memory");
    __builtin_amdgcn_sched_barrier(0);
    __builtin_amdgcn_s_setprio(1);
#pragma unroll
    for (int mi = 0; mi < 4; ++mi)
#pragma unroll
      for (int ni = 0; ni < 2; ++ni) {
        acc[mi + 4][ni + 2] = MFMA_BF16(aH[mi][0], bH[ni][0], acc[mi + 4][ni + 2], 0, 0, 0);
        acc[mi + 4][ni + 2] = MFMA_BF16(aH[mi][1], bH[ni][1], acc[mi + 4][ni + 2], 0, 0, 0);
      }
    __builtin_amdgcn_s_setprio(0);
    __builtin_amdgcn_s_barrier();

    // ===== Phase 3: stage A0(t+2); boundary vmcnt+barrier BEFORE Q3;
    //       prefetch aL(t+1) from other buffer (hides under Q3); MFMA Q3 =====
    // A0(t+2) -> buf p A-half0: last reads aH(t)@P1 retired by P2 lgkm + barrier. SAFE.
    if (t + 2 < NT) { STAGE_A(0, 0, t + 2); STAGE_A(0, 1, t + 2); }
    if (t + 2 < NT)      asm volatile("s_waitcnt vmcnt(2)" ::: "memory");
    else if (t + 1 < NT) asm volatile("s_waitcnt vmcnt(0)" ::: "memory");
    __builtin_amdgcn_s_barrier();  // all of tile t+1 resident & cross-wave visible
    if (t + 1 < NT) {
#pragma unroll
      for (int mi = 0; mi < 4; ++mi) {  // aL regs dead since Q1; Q3 uses aH,bL
        aL[mi][0] = *(const bf16x8_t*)(a1n + mi * 2048 + c0);
        aL[mi][1] = *(const bf16x8_t*)(a1n + mi * 2048 + c1);
      }
    }
    __builtin_amdgcn_sched_barrier(0);
    __builtin_amdgcn_s_setprio(1);
#pragma unroll
    for (int mi = 0; mi < 4; ++mi)
#pragma unroll
      for (int ni = 0; ni < 2; ++ni) {
        acc[mi + 4][ni] = MFMA_BF16(aH[mi][0], bL[ni][0], acc[mi + 4][ni], 0, 0, 0);
        acc[mi + 4][ni] = MFMA_BF16(aH[mi][1], bL[ni][1], acc[mi + 4][ni], 0, 0, 0);
      }
    __builtin_amdgcn_s_setprio(0);
    __builtin_amdgcn_s_barrier();
  }

  // ---- epilogue: C/D layout col=lane&15, row=(lane>>4)*4+reg ----
  const int row0 = m0 + wr * 128 + (lane >> 4) * 4;
  const int col0 = n0 + wc * 64 + lane15;
#pragma unroll
  for (int mi = 0; mi < 8; ++mi)
#pragma unroll
    for (int ni = 0; ni < 4; ++ni) {
#pragma unroll
      for (int k = 0; k < 4; ++k)
        out[(size_t)(row0 + mi * 16 + k) * N + col0 + ni * 16] = acc[mi][ni][k];
    }
#undef STAGE_A
#undef STAGE_B
}

// ------------------------------------------- fallback (no workspace): fused GEMM
__global__ __launch_bounds__(256) void gemm_fallback_kernel(const float* __restrict__ x,
                                                            const float* __restrict__ base,
                                                            const int* __restrict__ mask,
                                                            const float* __restrict__ coeffp,
                                                            float* __restrict__ out,
                                                            int M, int N, int K) {
  __shared__ __align__(16) __hip_bfloat16 As[128 * 32];
  __shared__ __align__(16) __hip_bfloat16 Bs[128 * 32];
  const float coeff = coeffp[0];
  const int ntn = N >> 7;
  const int tm = blockIdx.x / ntn, tn = blockIdx.x - tm * ntn;
  const int m0 = tm << 7, n0 = tn << 7;
  const int tid = threadIdx.x, lane = tid & 63, wave = tid >> 6;
  const int wr = wave >> 1, wc = wave & 1;

  f32x4_t acc[4][4];
  const f32x4_t zero = {0.0f, 0.0f, 0.0f, 0.0f};
#pragma unroll
  for (int i = 0; i < 4; ++i)
#pragma unroll
    for (int j = 0; j < 4; ++j) acc[i][j] = zero;

  const int arow = tid >> 1;
  const int acol = (tid & 1) * 16;
  const int bkk = tid & 31;
  const int bnb = (tid >> 5) * 16;
  const int arow_base = wr * 64 + (lane & 15);
  const int bcol_base = wc * 64 + (lane & 15);
  const int koff = (lane >> 4) * 8;

  for (int k0 = 0; k0 < K; k0 += 32) {
    __syncthreads();
    {
      const float* src = &x[(size_t)(m0 + arow) * K + k0 + acol];
      __hip_bfloat16 tmp[16];
#pragma unroll
      for (int j = 0; j < 16; ++j) tmp[j] = __float2bfloat16(src[j]);
      *(u16x8_t*)&As[arow * 32 + acol] = *(const u16x8_t*)&tmp[0];
      *(u16x8_t*)&As[arow * 32 + acol + 8] = *(const u16x8_t*)&tmp[8];
    }
    {
      const float* bsrc = &base[(size_t)(k0 + bkk) * N + n0 + bnb];
      const int* msrc = &mask[(size_t)(k0 + bkk) * N + n0 + bnb];
#pragma unroll
      for (int j = 0; j < 16; ++j) {
        float w = bsrc[j] + (msrc[j] ? coeff : -coeff);
        Bs[(bnb + j) * 32 + bkk] = __float2bfloat16(w);
      }
    }
    __syncthreads();

    bf16x8_t a[4], b[4];
#pragma unroll
    for (int mi = 0; mi < 4; ++mi)
      a[mi] = *(const bf16x8_t*)&As[(arow_base + mi * 16) * 32 + koff];
#pragma unroll
    for (int ni = 0; ni < 4; ++ni)
      b[ni] = *(const bf16x8_t*)&Bs[(bcol_base + ni * 16) * 32 + koff];
#pragma unroll
    for (int mi = 0; mi < 4; ++mi)
#pragma unroll
      for (int ni = 0; ni < 4; ++ni)
        acc[mi][ni] = MFMA_BF16(a[mi], b[ni], acc[mi][ni], 0, 0, 0);
  }

  const int row0 = m0 + wr * 64 + (lane >> 4) * 4;
  const int col0 = n0 + wc * 64 + (lane & 15);
#pragma unroll
  for (int mi = 0; mi < 4; ++mi)
#pragma unroll
    for (int ni = 0; ni < 4; ++ni) {
      int r = row0 + mi * 16;
      int c = col0 + ni * 16;
#pragma unroll
      for (int k = 0; k < 4; ++k) out[(size_t)(r + k) * N + c] = acc[mi][ni][k];
    }
}

// --------------------------------------------------------------------- launcher
extern "C" void kernel_launch(void* const* d_in, const int* in_sizes, int n_in,
                              void* d_out, int out_size, void* d_ws, size_t ws_size,
                              hipStream_t stream) {
  const int B = 4, S = 2048, DIN = 4096, DOUT = 4096;
  const int M = B * S;  // 8192
  const float* x = (const float*)d_in[0];
  const float* base = (const float*)d_in[1];
  const int* mask = (const int*)d_in[2];
  const float* coeff = (const float*)d_in[3];
  float* out = (float*)d_out;

  const size_t xb_bytes = (size_t)M * DIN * sizeof(__hip_bfloat16);
  const size_t wt_bytes = (size_t)DIN * DOUT * sizeof(__hip_bfloat16);

  if (ws_size >= xb_bytes + wt_bytes) {
    __hip_bfloat16* xb = (__hip_bfloat16*)d_ws;
    __hip_bfloat16* wt = (__hip_bfloat16*)((char*)d_ws + xb_bytes);
    cast_x_kernel<<<(M * DIN) / (256 * 8), 256, 0, stream>>>(x, xb);
    make_wt_kernel<<<dim3(DOUT / 32, DIN / 32), 256, 0, stream>>>(base, mask, coeff, wt, DIN, DOUT);
    const int n_tiles = (M / 256) * (DOUT / 256);  // 512
    gemm256_kernel<<<n_tiles, 512, 0, stream>>>(xb, wt, out, M, DOUT, DIN);
  } else {
    const int n_tiles = (M / 128) * (DOUT / 128);
    gemm_fallback_kernel<<<n_tiles, 256, 0, stream>>>(x, base, mask, coeff, out, M, DOUT, DIN);
  }
}

// Round 7
// 366.296 us; speedup vs baseline: 1.0663x; 1.0663x over previous
//
#include <hip/hip_runtime.h>
#include <hip/hip_bf16.h>
#include <stdint.h>

// BinaryDiff: out = x @ (base + coeff*(2*mask-1))
// M=8192, K=4096, N=4096. fp32 in/out, bf16 MFMA compute.
// GEMM: 256x256 tile, BK=64, 8 waves (2Mx4N), 4 phases/K-tile, st-swizzled LDS.
// R7 = R3 + read-one-phase-ahead with COUNTED lgkmcnt (the m201 "lgkmcnt(8)"
// mechanism): each phase's fragments are issued at the PREVIOUS phase top and
// are a full barrier+MFMA-cluster old when consumed. Counts: P0 lgkm(4),
// P1 lgkm(8), P2 lgkm(0). Stage slots and vmcnt(2) identical to R3.

typedef short bf16x8_t __attribute__((ext_vector_type(8)));
typedef float f32x4_t __attribute__((ext_vector_type(4)));
typedef unsigned short u16x8_t __attribute__((ext_vector_type(8)));

#define GLD_LDS16(gptr, lptr)                                                        \
  __builtin_amdgcn_global_load_lds(                                                  \
      (const __attribute__((address_space(1))) void*)(gptr),                         \
      (__attribute__((address_space(3))) void*)(lptr), 16, 0, 0)

#define MFMA_BF16 __builtin_amdgcn_mfma_f32_16x16x32_bf16

// ---------------------------------------------------------------- prep: x -> bf16
__global__ __launch_bounds__(256) void cast_x_kernel(const float* __restrict__ x,
                                                     __hip_bfloat16* __restrict__ xb) {
  size_t i = ((size_t)blockIdx.x * 256 + threadIdx.x) * 8;
  f32x4_t v0 = *(const f32x4_t*)&x[i];
  f32x4_t v1 = *(const f32x4_t*)&x[i + 4];
  __hip_bfloat16 tmp[8];
#pragma unroll
  for (int j = 0; j < 4; ++j) tmp[j] = __float2bfloat16(v0[j]);
#pragma unroll
  for (int j = 0; j < 4; ++j) tmp[4 + j] = __float2bfloat16(v1[j]);
  *(u16x8_t*)&xb[i] = *(const u16x8_t*)tmp;
}

// ------------------------------------- prep: Wt[n][k] = bf16(base[k][n] +/- coeff)
__global__ __launch_bounds__(256) void make_wt_kernel(const float* __restrict__ base,
                                                      const int* __restrict__ mask,
                                                      const float* __restrict__ coeffp,
                                                      __hip_bfloat16* __restrict__ wt,
                                                      int K, int N) {
  __shared__ float tile[32][33];
  const float coeff = coeffp[0];
  const int n0 = blockIdx.x * 32, k0 = blockIdx.y * 32;
  const int tx = threadIdx.x & 31;
  const int ty = threadIdx.x >> 5;
#pragma unroll
  for (int j = 0; j < 4; ++j) {
    int k = k0 + ty + j * 8;
    size_t idx = (size_t)k * N + n0 + tx;
    float b = base[idx];
    int m = mask[idx];
    tile[ty + j * 8][tx] = b + (m ? coeff : -coeff);
  }
  __syncthreads();
#pragma unroll
  for (int j = 0; j < 4; ++j) {
    int n = n0 + ty + j * 8;
    wt[(size_t)n * K + k0 + tx] = __float2bfloat16(tile[tx][ty + j * 8]);
  }
}

// ------------------------------------------------- main GEMM: 256^2 8-phase bf16
// A = xb[M][K], B = wt[N][K] (W^T), C = out[M][N] fp32.
__global__ __launch_bounds__(512, 2) void gemm256_kernel(const __hip_bfloat16* __restrict__ xb,
                                                         const __hip_bfloat16* __restrict__ wt,
                                                         float* __restrict__ out,
                                                         int M, int N, int K) {
  __shared__ __align__(16) __hip_bfloat16 As[2 * 256 * 64];  // 64 KiB (2 x 32 KiB)
  __shared__ __align__(16) __hip_bfloat16 Bs[2 * 256 * 64];  // 64 KiB (2 x 32 KiB)
  const int NT = K >> 6;  // K-tiles of 64

  // XCD-aware swizzle (nwg = 512, %8==0 -> simple bijective form)
  const int nwg = gridDim.x;
  int bid = blockIdx.x;
  int sw = bid;
  if ((nwg & 7) == 0) {
    int per = nwg >> 3;
    sw = (bid & 7) * per + (bid >> 3);
  }
  const int ntn = N >> 8;
  const int tm = sw / ntn, tn = sw - tm * ntn;
  const int m0 = tm << 8, n0 = tn << 8;

  const int tid = threadIdx.x;
  const int lane = tid & 63;
  const int wave = tid >> 6;  // 0..7
  const int wr = wave >> 2;   // 0..1  (M direction, 128 rows each)
  const int wc = wave & 3;    // 0..3  (N direction, 64 cols each)

  // ---- staging: linear LDS dest, pre-swizzled global source (rule #21) ----
  const int lrow = lane >> 3;                 // 0..7 (row within 8-row chunk)
  const int lcol = ((lane & 7) ^ lrow) << 3;  // source col (elems), 16B-slot swizzle
  uint32_t aOff[2][2], bOff[2][2];            // global element offsets (static idx only)
#pragma unroll
  for (int h = 0; h < 2; ++h)
#pragma unroll
    for (int j = 0; j < 2; ++j) {
      aOff[h][j] = (uint32_t)((m0 + h * 128 + wave * 16 + j * 8 + lrow) * K + lcol);
      bOff[h][j] = (uint32_t)((n0 + h * 128 + wave * 16 + j * 8 + lrow) * K + lcol);
    }

// one half-tile = 2 x global_load_lds per wave (8 waves x 2 x 1KiB = 16 KiB)
// buffer half = 256 rows * 128 B = 32768 B -> (tau&1)<<15
#define STAGE_A(h, j, tau)                                                       \
  GLD_LDS16(xb + (size_t)aOff[h][j] + (size_t)(tau) * 64,                        \
            (char*)As + (((tau) & 1) << 15) + ((h) * 16384 + wave * 2048 + (j) * 1024))
#define STAGE_B(h, j, tau)                                                       \
  GLD_LDS16(wt + (size_t)bOff[h][j] + (size_t)(tau) * 64,                        \
            (char*)Bs + (((tau) & 1) << 15) + ((h) * 16384 + wave * 2048 + (j) * 1024))

  // ---- prologue: tile0 all 4 halves + tile1 A0 = 5 halves (10 loads) ----
  STAGE_A(0, 0, 0); STAGE_A(0, 1, 0);
  STAGE_A(1, 0, 0); STAGE_A(1, 1, 0);
  STAGE_B(0, 0, 0); STAGE_B(0, 1, 0);
  STAGE_B(1, 0, 0); STAGE_B(1, 1, 0);
  STAGE_A(0, 0, 1); STAGE_A(0, 1, 1);
  asm volatile("s_waitcnt vmcnt(2)" ::: "memory");  // tile0's 8 loads landed
  __builtin_amdgcn_s_barrier();

  // ---- ds_read addressing: XOR-swizzled (row&7 == lane&7 on fragment rows) ----
  const int lane15 = lane & 15;
  const int swz = (lane & 7) << 4;
  const int c0 = (((lane >> 4) << 4)) ^ swz;      // ks=0 col byte (slots 0..3)
  const int c1 = (64 + ((lane >> 4) << 4)) ^ swz; // ks=1 col byte (slots 4..7)
  const int aRowB = (wr * 128 + lane15) * 128;    // byte row base within buffer
  const int bRowB = (wc * 64 + lane15) * 128;

  f32x4_t acc[8][4];
  const f32x4_t zero = {0.0f, 0.0f, 0.0f, 0.0f};
#pragma unroll
  for (int i = 0; i < 8; ++i)
#pragma unroll
    for (int j = 0; j < 4; ++j) acc[i][j] = zero;

  bf16x8_t aL[4][2], aH[4][2], bL[2][2], bH[2][2];

  // ---- pre-read aL(0)+bL(0) (12 reads; stay outstanding into P0's lgkm(4)) ----
  {
    const char* a0p = (const char*)As + aRowB;
    const char* b0p = (const char*)Bs + bRowB;
#pragma unroll
    for (int mi = 0; mi < 4; ++mi) {
      aL[mi][0] = *(const bf16x8_t*)(a0p + mi * 2048 + c0);
      aL[mi][1] = *(const bf16x8_t*)(a0p + mi * 2048 + c1);
    }
#pragma unroll
    for (int ni = 0; ni < 2; ++ni) {
      bL[ni][0] = *(const bf16x8_t*)(b0p + ni * 2048 + c0);
      bL[ni][1] = *(const bf16x8_t*)(b0p + ni * 2048 + c1);
    }
  }

  for (int t = 0; t < NT; ++t) {
    const int p = t & 1;
    const char* a0 = (const char*)As + (p << 15) + aRowB;
    const char* b0 = (const char*)Bs + (p << 15) + bRowB;

    // ===== Phase 0: read bH (for Q1/Q2); stage A1(t+1); lgkm(4); MFMA Q0 =====
#pragma unroll
    for (int ni = 0; ni < 2; ++ni) {
      bH[ni][0] = *(const bf16x8_t*)(b0 + (ni + 2) * 2048 + c0);
      bH[ni][1] = *(const bf16x8_t*)(b0 + (ni + 2) * 2048 + c1);
    }
    if (t + 1 < NT) { STAGE_A(1, 0, t + 1); STAGE_A(1, 1, t + 1); }
    __builtin_amdgcn_s_barrier();
    // outstanding: 12 (aL/bL from P3(t-1) or prologue) + 4 (bH) -> retire the 12
    asm volatile("s_waitcnt lgkmcnt(4)" ::: "memory");
    __builtin_amdgcn_sched_barrier(0);
    __builtin_amdgcn_s_setprio(1);
#pragma unroll
    for (int mi = 0; mi < 4; ++mi)
#pragma unroll
      for (int ni = 0; ni < 2; ++ni) {
        acc[mi][ni] = MFMA_BF16(aL[mi][0], bL[ni][0], acc[mi][ni], 0, 0, 0);
        acc[mi][ni] = MFMA_BF16(aL[mi][1], bL[ni][1], acc[mi][ni], 0, 0, 0);
      }
    __builtin_amdgcn_s_setprio(0);
    __builtin_amdgcn_s_barrier();

    // ===== Phase 1: read aH (for Q2/Q3); stage B0(t+1); lgkm(8); MFMA Q1 =====
#pragma unroll
    for (int mi = 0; mi < 4; ++mi) {
      aH[mi][0] = *(const bf16x8_t*)(a0 + (mi + 4) * 2048 + c0);
      aH[mi][1] = *(const bf16x8_t*)(a0 + (mi + 4) * 2048 + c1);
    }
    if (t + 1 < NT) { STAGE_B(0, 0, t + 1); STAGE_B(0, 1, t + 1); }
    __builtin_amdgcn_s_barrier();
    // outstanding: 4 (bH) + 8 (aH) -> retire bH, keep aH in flight
    asm volatile("s_waitcnt lgkmcnt(8)" ::: "memory");
    __builtin_amdgcn_sched_barrier(0);
    __builtin_amdgcn_s_setprio(1);
#pragma unroll
    for (int mi = 0; mi < 4; ++mi)
#pragma unroll
      for (int ni = 0; ni < 2; ++ni) {
        acc[mi][ni + 2] = MFMA_BF16(aL[mi][0], bH[ni][0], acc[mi][ni + 2], 0, 0, 0);
        acc[mi][ni + 2] = MFMA_BF16(aL[mi][1], bH[ni][1], acc[mi][ni + 2], 0, 0, 0);
      }
    __builtin_amdgcn_s_setprio(0);
    __builtin_amdgcn_s_barrier();

    // ===== Phase 2: stage B1(t+1); lgkm(0) (aH, a phase old); MFMA Q2 =====
    if (t + 1 < NT) { STAGE_B(1, 0, t + 1); STAGE_B(1, 1, t + 1); }
    __builtin_amdgcn_s_barrier();
    asm volatile("s_waitcnt lgkmcnt(0)" ::: "memory");
    __builtin_amdgcn_sched_barrier(0);
    __builtin_amdgcn_s_setprio(1);
#pragma unroll
    for (int mi = 0; mi < 4; ++mi)
#pragma unroll
      for (int ni = 0; ni < 2; ++ni) {
        acc[mi + 4][ni + 2] = MFMA_BF16(aH[mi][0], bH[ni][0], acc[mi + 4][ni + 2], 0, 0, 0);
        acc[mi + 4][ni + 2] = MFMA_BF16(aH[mi][1], bH[ni][1], acc[mi + 4][ni + 2], 0, 0, 0);
      }
    __builtin_amdgcn_s_setprio(0);
    __builtin_amdgcn_s_barrier();

    // ===== Phase 3: stage A0(t+2); vmcnt(2); BAR; MFMA Q3 (old aH x bL);
    //       then read aL/bL(t+1) (12 reads, retire at P0(t+1)'s lgkm(4)) =====
    // A0(t+2) -> buf p A-half0: last reads aH(t)@P1-top retired by P2 lgkm. SAFE.
    if (t + 2 < NT) {
      STAGE_A(0, 0, t + 2); STAGE_A(0, 1, t + 2);
      asm volatile("s_waitcnt vmcnt(2)" ::: "memory");  // all of t+1 landed
    } else if (t + 1 < NT) {
      asm volatile("s_waitcnt vmcnt(0)" ::: "memory");  // tail drain
    }
    __builtin_amdgcn_s_barrier();  // t+1 resident & cross-wave visible
    __builtin_amdgcn_sched_barrier(0);
    __builtin_amdgcn_s_setprio(1);
#pragma unroll
    for (int mi = 0; mi < 4; ++mi)
#pragma unroll
      for (int ni = 0; ni < 2; ++ni) {
        acc[mi + 4][ni] = MFMA_BF16(aH[mi][0], bL[ni][0], acc[mi + 4][ni], 0, 0, 0);
        acc[mi + 4][ni] = MFMA_BF16(aH[mi][1], bL[ni][1], acc[mi + 4][ni], 0, 0, 0);
      }
    __builtin_amdgcn_s_setprio(0);
    if (t + 1 < NT) {  // read next tile's aL/bL from the other buffer
      const char* a1n = (const char*)As + ((p ^ 1) << 15) + aRowB;
      const char* b1n = (const char*)Bs + ((p ^ 1) << 15) + bRowB;
#pragma unroll
      for (int mi = 0; mi < 4; ++mi) {
        aL[mi][0] = *(const bf16x8_t*)(a1n + mi * 2048 + c0);
        aL[mi][1] = *(const bf16x8_t*)(a1n + mi * 2048 + c1);
      }
#pragma unroll
      for (int ni = 0; ni < 2; ++ni) {
        bL[ni][0] = *(const bf16x8_t*)(b1n + ni * 2048 + c0);
        bL[ni][1] = *(const bf16x8_t*)(b1n + ni * 2048 + c1);
      }
    }
    __builtin_amdgcn_s_barrier();
  }

  // ---- epilogue: C/D layout col=lane&15, row=(lane>>4)*4+reg ----
  const int row0 = m0 + wr * 128 + (lane >> 4) * 4;
  const int col0 = n0 + wc * 64 + lane15;
#pragma unroll
  for (int mi = 0; mi < 8; ++mi)
#pragma unroll
    for (int ni = 0; ni < 4; ++ni) {
#pragma unroll
      for (int k = 0; k < 4; ++k)
        out[(size_t)(row0 + mi * 16 + k) * N + col0 + ni * 16] = acc[mi][ni][k];
    }
#undef STAGE_A
#undef STAGE_B
}

// ------------------------------------------- fallback (no workspace): fused GEMM
__global__ __launch_bounds__(256) void gemm_fallback_kernel(const float* __restrict__ x,
                                                            const float* __restrict__ base,
                                                            const int* __restrict__ mask,
                                                            const float* __restrict__ coeffp,
                                                            float* __restrict__ out,
                                                            int M, int N, int K) {
  __shared__ __align__(16) __hip_bfloat16 As[128 * 32];
  __shared__ __align__(16) __hip_bfloat16 Bs[128 * 32];
  const float coeff = coeffp[0];
  const int ntn = N >> 7;
  const int tm = blockIdx.x / ntn, tn = blockIdx.x - tm * ntn;
  const int m0 = tm << 7, n0 = tn << 7;
  const int tid = threadIdx.x, lane = tid & 63, wave = tid >> 6;
  const int wr = wave >> 1, wc = wave & 1;

  f32x4_t acc[4][4];
  const f32x4_t zero = {0.0f, 0.0f, 0.0f, 0.0f};
#pragma unroll
  for (int i = 0; i < 4; ++i)
#pragma unroll
    for (int j = 0; j < 4; ++j) acc[i][j] = zero;

  const int arow = tid >> 1;
  const int acol = (tid & 1) * 16;
  const int bkk = tid & 31;
  const int bnb = (tid >> 5) * 16;
  const int arow_base = wr * 64 + (lane & 15);
  const int bcol_base = wc * 64 + (lane & 15);
  const int koff = (lane >> 4) * 8;

  for (int k0 = 0; k0 < K; k0 += 32) {
    __syncthreads();
    {
      const float* src = &x[(size_t)(m0 + arow) * K + k0 + acol];
      __hip_bfloat16 tmp[16];
#pragma unroll
      for (int j = 0; j < 16; ++j) tmp[j] = __float2bfloat16(src[j]);
      *(u16x8_t*)&As[arow * 32 + acol] = *(const u16x8_t*)&tmp[0];
      *(u16x8_t*)&As[arow * 32 + acol + 8] = *(const u16x8_t*)&tmp[8];
    }
    {
      const float* bsrc = &base[(size_t)(k0 + bkk) * N + n0 + bnb];
      const int* msrc = &mask[(size_t)(k0 + bkk) * N + n0 + bnb];
#pragma unroll
      for (int j = 0; j < 16; ++j) {
        float w = bsrc[j] + (msrc[j] ? coeff : -coeff);
        Bs[(bnb + j) * 32 + bkk] = __float2bfloat16(w);
      }
    }
    __syncthreads();

    bf16x8_t a[4], b[4];
#pragma unroll
    for (int mi = 0; mi < 4; ++mi)
      a[mi] = *(const bf16x8_t*)&As[(arow_base + mi * 16) * 32 + koff];
#pragma unroll
    for (int ni = 0; ni < 4; ++ni)
      b[ni] = *(const bf16x8_t*)&Bs[(bcol_base + ni * 16) * 32 + koff];
#pragma unroll
    for (int mi = 0; mi < 4; ++mi)
#pragma unroll
      for (int ni = 0; ni < 4; ++ni)
        acc[mi][ni] = MFMA_BF16(a[mi], b[ni], acc[mi][ni], 0, 0, 0);
  }

  const int row0 = m0 + wr * 64 + (lane >> 4) * 4;
  const int col0 = n0 + wc * 64 + (lane & 15);
#pragma unroll
  for (int mi = 0; mi < 4; ++mi)
#pragma unroll
    for (int ni = 0; ni < 4; ++ni) {
      int r = row0 + mi * 16;
      int c = col0 + ni * 16;
#pragma unroll
      for (int k = 0; k < 4; ++k) out[(size_t)(r + k) * N + c] = acc[mi][ni][k];
    }
}

// --------------------------------------------------------------------- launcher
extern "C" void kernel_launch(void* const* d_in, const int* in_sizes, int n_in,
                              void* d_out, int out_size, void* d_ws, size_t ws_size,
                              hipStream_t stream) {
  const int B = 4, S = 2048, DIN = 4096, DOUT = 4096;
  const int M = B * S;  // 8192
  const float* x = (const float*)d_in[0];
  const float* base = (const float*)d_in[1];
  const int* mask = (const int*)d_in[2];
  const float* coeff = (const float*)d_in[3];
  float* out = (float*)d_out;

  const size_t xb_bytes = (size_t)M * DIN * sizeof(__hip_bfloat16);
  const size_t wt_bytes = (size_t)DIN * DOUT * sizeof(__hip_bfloat16);

  if (ws_size >= xb_bytes + wt_bytes) {
    __hip_bfloat16* xb = (__hip_bfloat16*)d_ws;
    __hip_bfloat16* wt = (__hip_bfloat16*)((char*)d_ws + xb_bytes);
    cast_x_kernel<<<(M * DIN) / (256 * 8), 256, 0, stream>>>(x, xb);
    make_wt_kernel<<<dim3(DOUT / 32, DIN / 32), 256, 0, stream>>>(base, mask, coeff, wt, DIN, DOUT);
    const int n_tiles = (M / 256) * (DOUT / 256);  // 512
    gemm256_kernel<<<n_tiles, 512, 0, stream>>>(xb, wt, out, M, DOUT, DIN);
  } else {
    const int n_tiles = (M / 128) * (DOUT / 128);
    gemm_fallback_kernel<<<n_tiles, 256, 0, stream>>>(x, base, mask, coeff, out, M, DOUT, DIN);
  }
}

// Round 8
// 362.675 us; speedup vs baseline: 1.0770x; 1.0100x over previous
//
#include <hip/hip_runtime.h>
#include <hip/hip_bf16.h>
#include <stdint.h>

// BinaryDiff: out = x @ (base + coeff*(2*mask-1))
// M=8192, K=4096, N=4096. fp32 in/out, bf16 MFMA compute.
// R8 = R3 frame (best: 295us GEMM) with MFMA shape 32x32x16 instead of 16x16x32.
// Same 256x256 tile, BK=64, 8 waves (2Mx4N), 4 phases/K-tile, same stage slots,
// same vmcnt(2), same XOR-swizzled LDS. Per wave: 4x2 tiles of 32x32, 4 k-steps.
// A-frag: row=lane&31, k=(lane>>5)*8. C/D: col=lane&31,
// row=(reg&3)+8*(reg>>2)+4*(lane>>5) (m74/m101-verified).

typedef short bf16x8_t __attribute__((ext_vector_type(8)));
typedef float f32x4_t __attribute__((ext_vector_type(4)));
typedef float f32x16_t __attribute__((ext_vector_type(16)));
typedef unsigned short u16x8_t __attribute__((ext_vector_type(8)));

#define GLD_LDS16(gptr, lptr)                                                        \
  __builtin_amdgcn_global_load_lds(                                                  \
      (const __attribute__((address_space(1))) void*)(gptr),                         \
      (__attribute__((address_space(3))) void*)(lptr), 16, 0, 0)

#define MFMA32 __builtin_amdgcn_mfma_f32_32x32x16_bf16
#define MFMA_BF16 __builtin_amdgcn_mfma_f32_16x16x32_bf16

// ---------------------------------------------------------------- prep: x -> bf16
__global__ __launch_bounds__(256) void cast_x_kernel(const float* __restrict__ x,
                                                     __hip_bfloat16* __restrict__ xb) {
  size_t i = ((size_t)blockIdx.x * 256 + threadIdx.x) * 8;
  f32x4_t v0 = *(const f32x4_t*)&x[i];
  f32x4_t v1 = *(const f32x4_t*)&x[i + 4];
  __hip_bfloat16 tmp[8];
#pragma unroll
  for (int j = 0; j < 4; ++j) tmp[j] = __float2bfloat16(v0[j]);
#pragma unroll
  for (int j = 0; j < 4; ++j) tmp[4 + j] = __float2bfloat16(v1[j]);
  *(u16x8_t*)&xb[i] = *(const u16x8_t*)tmp;
}

// ------------------------------------- prep: Wt[n][k] = bf16(base[k][n] +/- coeff)
__global__ __launch_bounds__(256) void make_wt_kernel(const float* __restrict__ base,
                                                      const int* __restrict__ mask,
                                                      const float* __restrict__ coeffp,
                                                      __hip_bfloat16* __restrict__ wt,
                                                      int K, int N) {
  __shared__ float tile[32][33];
  const float coeff = coeffp[0];
  const int n0 = blockIdx.x * 32, k0 = blockIdx.y * 32;
  const int tx = threadIdx.x & 31;
  const int ty = threadIdx.x >> 5;
#pragma unroll
  for (int j = 0; j < 4; ++j) {
    int k = k0 + ty + j * 8;
    size_t idx = (size_t)k * N + n0 + tx;
    float b = base[idx];
    int m = mask[idx];
    tile[ty + j * 8][tx] = b + (m ? coeff : -coeff);
  }
  __syncthreads();
#pragma unroll
  for (int j = 0; j < 4; ++j) {
    int n = n0 + ty + j * 8;
    wt[(size_t)n * K + k0 + tx] = __float2bfloat16(tile[tx][ty + j * 8]);
  }
}

// ------------------------------------------------- main GEMM: 256^2, 32x32 MFMA
// A = xb[M][K], B = wt[N][K] (W^T), C = out[M][N] fp32.
__global__ __launch_bounds__(512, 2) void gemm256_kernel(const __hip_bfloat16* __restrict__ xb,
                                                         const __hip_bfloat16* __restrict__ wt,
                                                         float* __restrict__ out,
                                                         int M, int N, int K) {
  __shared__ __align__(16) __hip_bfloat16 As[2 * 256 * 64];  // 64 KiB (2 x 32 KiB)
  __shared__ __align__(16) __hip_bfloat16 Bs[2 * 256 * 64];  // 64 KiB (2 x 32 KiB)
  const int NT = K >> 6;  // K-tiles of 64

  // XCD-aware swizzle (nwg = 512, %8==0 -> simple bijective form)
  const int nwg = gridDim.x;
  int bid = blockIdx.x;
  int sw = bid;
  if ((nwg & 7) == 0) {
    int per = nwg >> 3;
    sw = (bid & 7) * per + (bid >> 3);
  }
  const int ntn = N >> 8;
  const int tm = sw / ntn, tn = sw - tm * ntn;
  const int m0 = tm << 8, n0 = tn << 8;

  const int tid = threadIdx.x;
  const int lane = tid & 63;
  const int wave = tid >> 6;  // 0..7
  const int wr = wave >> 2;   // 0..1  (M direction, 128 rows each)
  const int wc = wave & 3;    // 0..3  (N direction, 64 cols each)

  // ---- staging: linear LDS dest, pre-swizzled global source (rule #21) ----
  const int lrow = lane >> 3;                 // 0..7 (row within 8-row chunk)
  const int lcol = ((lane & 7) ^ lrow) << 3;  // source col (elems), 16B-slot swizzle
  uint32_t aOff[2][2], bOff[2][2];            // global element offsets (static idx only)
#pragma unroll
  for (int h = 0; h < 2; ++h)
#pragma unroll
    for (int j = 0; j < 2; ++j) {
      aOff[h][j] = (uint32_t)((m0 + h * 128 + wave * 16 + j * 8 + lrow) * K + lcol);
      bOff[h][j] = (uint32_t)((n0 + h * 128 + wave * 16 + j * 8 + lrow) * K + lcol);
    }

// one half-tile = 2 x global_load_lds per wave (8 waves x 2 x 1KiB = 16 KiB)
// buffer half = 256 rows * 128 B = 32768 B -> (tau&1)<<15
#define STAGE_A(h, j, tau)                                                       \
  GLD_LDS16(xb + (size_t)aOff[h][j] + (size_t)(tau) * 64,                        \
            (char*)As + (((tau) & 1) << 15) + ((h) * 16384 + wave * 2048 + (j) * 1024))
#define STAGE_B(h, j, tau)                                                       \
  GLD_LDS16(wt + (size_t)bOff[h][j] + (size_t)(tau) * 64,                        \
            (char*)Bs + (((tau) & 1) << 15) + ((h) * 16384 + wave * 2048 + (j) * 1024))

  // ---- prologue: tile0 all 4 halves + tile1 A0 = 5 halves (10 loads) ----
  STAGE_A(0, 0, 0); STAGE_A(0, 1, 0);
  STAGE_A(1, 0, 0); STAGE_A(1, 1, 0);
  STAGE_B(0, 0, 0); STAGE_B(0, 1, 0);
  STAGE_B(1, 0, 0); STAGE_B(1, 1, 0);
  STAGE_A(0, 0, 1); STAGE_A(0, 1, 1);
  asm volatile("s_waitcnt vmcnt(2)" ::: "memory");  // tile0's 8 loads landed
  __builtin_amdgcn_s_barrier();

  // ---- ds_read addressing for 32x32x16 fragments, XOR-swizzled ----
  // row = (group)*32 + (lane&31); k-col byte for kstep s: s*32 + (lane>>5)*16
  const int lane31 = lane & 31;
  const int swz = (lane & 7) << 4;           // row&7 == lane&7
  const int kb = (lane >> 5) << 4;           // 0 or 16
  int cb[4];
#pragma unroll
  for (int s = 0; s < 4; ++s) cb[s] = (s * 32 + kb) ^ swz;
  const int aRowB = (wr * 128 + lane31) * 128;  // byte row base within buffer
  const int bRowB = (wc * 64 + lane31) * 128;

  f32x16_t acc[4][2];  // [rowgroup 0..3][colgroup 0..1], 128 regs
#pragma unroll
  for (int i = 0; i < 4; ++i)
#pragma unroll
    for (int j = 0; j < 2; ++j)
#pragma unroll
      for (int e = 0; e < 16; ++e) acc[i][j][e] = 0.0f;

  bf16x8_t aL[2][4], aH[2][4], bL[4], bH[4];

  for (int t = 0; t < NT; ++t) {
    const int p = t & 1;
    const char* a0 = (const char*)As + (p << 15) + aRowB;
    const char* b0 = (const char*)Bs + (p << 15) + bRowB;

    // ===== Phase 0: read aL(8)+bL(4); stage A1(t+1); lgkm0; MFMA Q0 (aL x bL) =====
#pragma unroll
    for (int g = 0; g < 2; ++g)
#pragma unroll
      for (int s = 0; s < 4; ++s)
        aL[g][s] = *(const bf16x8_t*)(a0 + g * 4096 + cb[s]);
#pragma unroll
    for (int s = 0; s < 4; ++s) bL[s] = *(const bf16x8_t*)(b0 + cb[s]);
    if (t + 1 < NT) { STAGE_A(1, 0, t + 1); STAGE_A(1, 1, t + 1); }
    __builtin_amdgcn_s_barrier();
    asm volatile("s_waitcnt lgkmcnt(0)" ::: "memory");
    __builtin_amdgcn_sched_barrier(0);
    __builtin_amdgcn_s_setprio(1);
#pragma unroll
    for (int s = 0; s < 4; ++s)
#pragma unroll
      for (int g = 0; g < 2; ++g)
        acc[g][0] = MFMA32(aL[g][s], bL[s], acc[g][0], 0, 0, 0);
    __builtin_amdgcn_s_setprio(0);
    __builtin_amdgcn_s_barrier();

    // ===== Phase 1: read bH(4); stage B0(t+1); lgkm0; MFMA Q1 (aL x bH) =====
#pragma unroll
    for (int s = 0; s < 4; ++s) bH[s] = *(const bf16x8_t*)(b0 + 4096 + cb[s]);
    if (t + 1 < NT) { STAGE_B(0, 0, t + 1); STAGE_B(0, 1, t + 1); }
    __builtin_amdgcn_s_barrier();
    asm volatile("s_waitcnt lgkmcnt(0)" ::: "memory");
    __builtin_amdgcn_sched_barrier(0);
    __builtin_amdgcn_s_setprio(1);
#pragma unroll
    for (int s = 0; s < 4; ++s)
#pragma unroll
      for (int g = 0; g < 2; ++g)
        acc[g][1] = MFMA32(aL[g][s], bH[s], acc[g][1], 0, 0, 0);
    __builtin_amdgcn_s_setprio(0);
    __builtin_amdgcn_s_barrier();

    // ===== Phase 2: read aH(8); stage B1(t+1); lgkm0; MFMA Q2 (aH x bH) =====
#pragma unroll
    for (int g = 0; g < 2; ++g)
#pragma unroll
      for (int s = 0; s < 4; ++s)
        aH[g][s] = *(const bf16x8_t*)(a0 + (g + 2) * 4096 + cb[s]);
    if (t + 1 < NT) { STAGE_B(1, 0, t + 1); STAGE_B(1, 1, t + 1); }
    __builtin_amdgcn_s_barrier();
    asm volatile("s_waitcnt lgkmcnt(0)" ::: "memory");
    __builtin_amdgcn_sched_barrier(0);
    __builtin_amdgcn_s_setprio(1);
#pragma unroll
    for (int s = 0; s < 4; ++s)
#pragma unroll
      for (int g = 0; g < 2; ++g)
        acc[g + 2][1] = MFMA32(aH[g][s], bH[s], acc[g + 2][1], 0, 0, 0);
    __builtin_amdgcn_s_setprio(0);
    __builtin_amdgcn_s_barrier();

    // ===== Phase 3: stage A0(t+2); vmcnt(2); BAR; MFMA Q3 (aH x bL) =====
    // A0(t+2) -> buf p A-half0: tile t's aL reads retired at P0's lgkm. SAFE.
    if (t + 2 < NT) {
      STAGE_A(0, 0, t + 2); STAGE_A(0, 1, t + 2);
      asm volatile("s_waitcnt vmcnt(2)" ::: "memory");  // all of t+1 landed
    } else if (t + 1 < NT) {
      asm volatile("s_waitcnt vmcnt(0)" ::: "memory");  // tail drain
    }
    __builtin_amdgcn_s_barrier();  // t+1 resident & cross-wave visible
    __builtin_amdgcn_sched_barrier(0);
    __builtin_amdgcn_s_setprio(1);
#pragma unroll
    for (int s = 0; s < 4; ++s)
#pragma unroll
      for (int g = 0; g < 2; ++g)
        acc[g + 2][0] = MFMA32(aH[g][s], bL[s], acc[g + 2][0], 0, 0, 0);
    __builtin_amdgcn_s_setprio(0);
    __builtin_amdgcn_s_barrier();
  }

  // ---- epilogue: 32x32 C/D layout: col=lane&31, row=(reg&3)+8*(reg>>2)+4*(lane>>5) ----
  const int row0 = m0 + wr * 128 + 4 * (lane >> 5);
  const int col0 = n0 + wc * 64 + lane31;
#pragma unroll
  for (int mi = 0; mi < 4; ++mi)
#pragma unroll
    for (int ni = 0; ni < 2; ++ni) {
#pragma unroll
      for (int reg = 0; reg < 16; ++reg) {
        int r = row0 + mi * 32 + (reg & 3) + 8 * (reg >> 2);
        out[(size_t)r * N + col0 + ni * 32] = acc[mi][ni][reg];
      }
    }
#undef STAGE_A
#undef STAGE_B
}

// ------------------------------------------- fallback (no workspace): fused GEMM
__global__ __launch_bounds__(256) void gemm_fallback_kernel(const float* __restrict__ x,
                                                            const float* __restrict__ base,
                                                            const int* __restrict__ mask,
                                                            const float* __restrict__ coeffp,
                                                            float* __restrict__ out,
                                                            int M, int N, int K) {
  __shared__ __align__(16) __hip_bfloat16 As[128 * 32];
  __shared__ __align__(16) __hip_bfloat16 Bs[128 * 32];
  const float coeff = coeffp[0];
  const int ntn = N >> 7;
  const int tm = blockIdx.x / ntn, tn = blockIdx.x - tm * ntn;
  const int m0 = tm << 7, n0 = tn << 7;
  const int tid = threadIdx.x, lane = tid & 63, wave = tid >> 6;
  const int wr = wave >> 1, wc = wave & 1;

  f32x4_t acc[4][4];
  const f32x4_t zero = {0.0f, 0.0f, 0.0f, 0.0f};
#pragma unroll
  for (int i = 0; i < 4; ++i)
#pragma unroll
    for (int j = 0; j < 4; ++j) acc[i][j] = zero;

  const int arow = tid >> 1;
  const int acol = (tid & 1) * 16;
  const int bkk = tid & 31;
  const int bnb = (tid >> 5) * 16;
  const int arow_base = wr * 64 + (lane & 15);
  const int bcol_base = wc * 64 + (lane & 15);
  const int koff = (lane >> 4) * 8;

  for (int k0 = 0; k0 < K; k0 += 32) {
    __syncthreads();
    {
      const float* src = &x[(size_t)(m0 + arow) * K + k0 + acol];
      __hip_bfloat16 tmp[16];
#pragma unroll
      for (int j = 0; j < 16; ++j) tmp[j] = __float2bfloat16(src[j]);
      *(u16x8_t*)&As[arow * 32 + acol] = *(const u16x8_t*)&tmp[0];
      *(u16x8_t*)&As[arow * 32 + acol + 8] = *(const u16x8_t*)&tmp[8];
    }
    {
      const float* bsrc = &base[(size_t)(k0 + bkk) * N + n0 + bnb];
      const int* msrc = &mask[(size_t)(k0 + bkk) * N + n0 + bnb];
#pragma unroll
      for (int j = 0; j < 16; ++j) {
        float w = bsrc[j] + (msrc[j] ? coeff : -coeff);
        Bs[(bnb + j) * 32 + bkk] = __float2bfloat16(w);
      }
    }
    __syncthreads();

    bf16x8_t a[4], b[4];
#pragma unroll
    for (int mi = 0; mi < 4; ++mi)
      a[mi] = *(const bf16x8_t*)&As[(arow_base + mi * 16) * 32 + koff];
#pragma unroll
    for (int ni = 0; ni < 4; ++ni)
      b[ni] = *(const bf16x8_t*)&Bs[(bcol_base + ni * 16) * 32 + koff];
#pragma unroll
    for (int mi = 0; mi < 4; ++mi)
#pragma unroll
      for (int ni = 0; ni < 4; ++ni)
        acc[mi][ni] = MFMA_BF16(a[mi], b[ni], acc[mi][ni], 0, 0, 0);
  }

  const int row0 = m0 + wr * 64 + (lane >> 4) * 4;
  const int col0 = n0 + wc * 64 + (lane & 15);
#pragma unroll
  for (int mi = 0; mi < 4; ++mi)
#pragma unroll
    for (int ni = 0; ni < 4; ++ni) {
      int r = row0 + mi * 16;
      int c = col0 + ni * 16;
#pragma unroll
      for (int k = 0; k < 4; ++k) out[(size_t)(r + k) * N + c] = acc[mi][ni][k];
    }
}

// --------------------------------------------------------------------- launcher
extern "C" void kernel_launch(void* const* d_in, const int* in_sizes, int n_in,
                              void* d_out, int out_size, void* d_ws, size_t ws_size,
                              hipStream_t stream) {
  const int B = 4, S = 2048, DIN = 4096, DOUT = 4096;
  const int M = B * S;  // 8192
  const float* x = (const float*)d_in[0];
  const float* base = (const float*)d_in[1];
  const int* mask = (const int*)d_in[2];
  const float* coeff = (const float*)d_in[3];
  float* out = (float*)d_out;

  const size_t xb_bytes = (size_t)M * DIN * sizeof(__hip_bfloat16);
  const size_t wt_bytes = (size_t)DIN * DOUT * sizeof(__hip_bfloat16);

  if (ws_size >= xb_bytes + wt_bytes) {
    __hip_bfloat16* xb = (__hip_bfloat16*)d_ws;
    __hip_bfloat16* wt = (__hip_bfloat16*)((char*)d_ws + xb_bytes);
    cast_x_kernel<<<(M * DIN) / (256 * 8), 256, 0, stream>>>(x, xb);
    make_wt_kernel<<<dim3(DOUT / 32, DIN / 32), 256, 0, stream>>>(base, mask, coeff, wt, DIN, DOUT);
    const int n_tiles = (M / 256) * (DOUT / 256);  // 512
    gemm256_kernel<<<n_tiles, 512, 0, stream>>>(xb, wt, out, M, DOUT, DIN);
  } else {
    const int n_tiles = (M / 128) * (DOUT / 128);
    gemm_fallback_kernel<<<n_tiles, 256, 0, stream>>>(x, base, mask, coeff, out, M, DOUT, DIN);
  }
}

// Round 9
// 316.060 us; speedup vs baseline: 1.2358x; 1.1475x over previous
//
#include <hip/hip_runtime.h>
#include <hip/hip_bf16.h>
#include <stdint.h>

// BinaryDiff: out = x @ (base + coeff*(2*mask-1))
// M=8192, K=4096, N=4096. fp32 in/out, bf16 MFMA compute.
// R9 = R3 frame (best: 295us GEMM, 16x16x32 MFMA, conflict-free XOR-swizzle)
// with 4 phases merged into 2 per K-tile: {Q0+Q1} and {Q2+Q3} (32 MFMA each).
// Halves barrier count (8->4/tile) and lgkm-drain points (4->2).
// Stage slots: P0: A1,B0,B1(t+1); P1: A0(t+2) + vmcnt(2) before BAR (R3-style).

typedef short bf16x8_t __attribute__((ext_vector_type(8)));
typedef float f32x4_t __attribute__((ext_vector_type(4)));
typedef unsigned short u16x8_t __attribute__((ext_vector_type(8)));

#define GLD_LDS16(gptr, lptr)                                                        \
  __builtin_amdgcn_global_load_lds(                                                  \
      (const __attribute__((address_space(1))) void*)(gptr),                         \
      (__attribute__((address_space(3))) void*)(lptr), 16, 0, 0)

#define MFMA_BF16 __builtin_amdgcn_mfma_f32_16x16x32_bf16

// ---------------------------------------------------------------- prep: x -> bf16
__global__ __launch_bounds__(256) void cast_x_kernel(const float* __restrict__ x,
                                                     __hip_bfloat16* __restrict__ xb) {
  size_t i = ((size_t)blockIdx.x * 256 + threadIdx.x) * 8;
  f32x4_t v0 = *(const f32x4_t*)&x[i];
  f32x4_t v1 = *(const f32x4_t*)&x[i + 4];
  __hip_bfloat16 tmp[8];
#pragma unroll
  for (int j = 0; j < 4; ++j) tmp[j] = __float2bfloat16(v0[j]);
#pragma unroll
  for (int j = 0; j < 4; ++j) tmp[4 + j] = __float2bfloat16(v1[j]);
  *(u16x8_t*)&xb[i] = *(const u16x8_t*)tmp;
}

// ------------------------------------- prep: Wt[n][k] = bf16(base[k][n] +/- coeff)
__global__ __launch_bounds__(256) void make_wt_kernel(const float* __restrict__ base,
                                                      const int* __restrict__ mask,
                                                      const float* __restrict__ coeffp,
                                                      __hip_bfloat16* __restrict__ wt,
                                                      int K, int N) {
  __shared__ float tile[32][33];
  const float coeff = coeffp[0];
  const int n0 = blockIdx.x * 32, k0 = blockIdx.y * 32;
  const int tx = threadIdx.x & 31;
  const int ty = threadIdx.x >> 5;
#pragma unroll
  for (int j = 0; j < 4; ++j) {
    int k = k0 + ty + j * 8;
    size_t idx = (size_t)k * N + n0 + tx;
    float b = base[idx];
    int m = mask[idx];
    tile[ty + j * 8][tx] = b + (m ? coeff : -coeff);
  }
  __syncthreads();
#pragma unroll
  for (int j = 0; j < 4; ++j) {
    int n = n0 + ty + j * 8;
    wt[(size_t)n * K + k0 + tx] = __float2bfloat16(tile[tx][ty + j * 8]);
  }
}

// ------------------------------------------------- main GEMM: 256^2, 2-phase/K-tile
// A = xb[M][K], B = wt[N][K] (W^T), C = out[M][N] fp32.
__global__ __launch_bounds__(512, 2) void gemm256_kernel(const __hip_bfloat16* __restrict__ xb,
                                                         const __hip_bfloat16* __restrict__ wt,
                                                         float* __restrict__ out,
                                                         int M, int N, int K) {
  __shared__ __align__(16) __hip_bfloat16 As[2 * 256 * 64];  // 64 KiB (2 x 32 KiB)
  __shared__ __align__(16) __hip_bfloat16 Bs[2 * 256 * 64];  // 64 KiB (2 x 32 KiB)
  const int NT = K >> 6;  // K-tiles of 64

  // XCD-aware swizzle (nwg = 512, %8==0 -> simple bijective form)
  const int nwg = gridDim.x;
  int bid = blockIdx.x;
  int sw = bid;
  if ((nwg & 7) == 0) {
    int per = nwg >> 3;
    sw = (bid & 7) * per + (bid >> 3);
  }
  const int ntn = N >> 8;
  const int tm = sw / ntn, tn = sw - tm * ntn;
  const int m0 = tm << 8, n0 = tn << 8;

  const int tid = threadIdx.x;
  const int lane = tid & 63;
  const int wave = tid >> 6;  // 0..7
  const int wr = wave >> 2;   // 0..1  (M direction, 128 rows each)
  const int wc = wave & 3;    // 0..3  (N direction, 64 cols each)

  // ---- staging: linear LDS dest, pre-swizzled global source (rule #21) ----
  const int lrow = lane >> 3;                 // 0..7 (row within 8-row chunk)
  const int lcol = ((lane & 7) ^ lrow) << 3;  // source col (elems), 16B-slot swizzle
  uint32_t aOff[2][2], bOff[2][2];            // global element offsets (static idx only)
#pragma unroll
  for (int h = 0; h < 2; ++h)
#pragma unroll
    for (int j = 0; j < 2; ++j) {
      aOff[h][j] = (uint32_t)((m0 + h * 128 + wave * 16 + j * 8 + lrow) * K + lcol);
      bOff[h][j] = (uint32_t)((n0 + h * 128 + wave * 16 + j * 8 + lrow) * K + lcol);
    }

// one half-tile = 2 x global_load_lds per wave (8 waves x 2 x 1KiB = 16 KiB)
// buffer half = 256 rows * 128 B = 32768 B -> (tau&1)<<15
#define STAGE_A(h, j, tau)                                                       \
  GLD_LDS16(xb + (size_t)aOff[h][j] + (size_t)(tau) * 64,                        \
            (char*)As + (((tau) & 1) << 15) + ((h) * 16384 + wave * 2048 + (j) * 1024))
#define STAGE_B(h, j, tau)                                                       \
  GLD_LDS16(wt + (size_t)bOff[h][j] + (size_t)(tau) * 64,                        \
            (char*)Bs + (((tau) & 1) << 15) + ((h) * 16384 + wave * 2048 + (j) * 1024))

  // ---- prologue: tile0 all 4 halves + tile1 A0 = 5 halves (10 loads) ----
  STAGE_A(0, 0, 0); STAGE_A(0, 1, 0);
  STAGE_A(1, 0, 0); STAGE_A(1, 1, 0);
  STAGE_B(0, 0, 0); STAGE_B(0, 1, 0);
  STAGE_B(1, 0, 0); STAGE_B(1, 1, 0);
  STAGE_A(0, 0, 1); STAGE_A(0, 1, 1);
  asm volatile("s_waitcnt vmcnt(2)" ::: "memory");  // tile0's 8 loads landed
  __builtin_amdgcn_s_barrier();

  // ---- ds_read addressing: XOR-swizzled (row&7 == lane&7 on fragment rows) ----
  const int lane15 = lane & 15;
  const int swz = (lane & 7) << 4;
  const int c0 = (((lane >> 4) << 4)) ^ swz;      // ks=0 col byte (slots 0..3)
  const int c1 = (64 + ((lane >> 4) << 4)) ^ swz; // ks=1 col byte (slots 4..7)
  const int aRowB = (wr * 128 + lane15) * 128;    // byte row base within buffer
  const int bRowB = (wc * 64 + lane15) * 128;

  f32x4_t acc[8][4];
  const f32x4_t zero = {0.0f, 0.0f, 0.0f, 0.0f};
#pragma unroll
  for (int i = 0; i < 8; ++i)
#pragma unroll
    for (int j = 0; j < 4; ++j) acc[i][j] = zero;

  bf16x8_t aL[4][2], aH[4][2], bL[2][2], bH[2][2];

  for (int t = 0; t < NT; ++t) {
    const int p = t & 1;
    const char* a0 = (const char*)As + (p << 15) + aRowB;
    const char* b0 = (const char*)Bs + (p << 15) + bRowB;

    // ===== Phase 0: read aL(8)+bL(4)+bH(4); stage A1,B0,B1(t+1);
    //       BAR; lgkm0; MFMA Q0 (aL x bL) + Q1 (aL x bH) =====
    // WAR: A1/B0/B1(t+1) -> buf p^1; last readers aH/bL/bH(t-1) retired at
    // their phases' lgkm0, >=1 barrier before these stages execute. SAFE.
#pragma unroll
    for (int mi = 0; mi < 4; ++mi) {
      aL[mi][0] = *(const bf16x8_t*)(a0 + mi * 2048 + c0);
      aL[mi][1] = *(const bf16x8_t*)(a0 + mi * 2048 + c1);
    }
#pragma unroll
    for (int ni = 0; ni < 2; ++ni) {
      bL[ni][0] = *(const bf16x8_t*)(b0 + ni * 2048 + c0);
      bL[ni][1] = *(const bf16x8_t*)(b0 + ni * 2048 + c1);
      bH[ni][0] = *(const bf16x8_t*)(b0 + (ni + 2) * 2048 + c0);
      bH[ni][1] = *(const bf16x8_t*)(b0 + (ni + 2) * 2048 + c1);
    }
    if (t + 1 < NT) {
      STAGE_A(1, 0, t + 1); STAGE_A(1, 1, t + 1);
      STAGE_B(0, 0, t + 1); STAGE_B(0, 1, t + 1);
      STAGE_B(1, 0, t + 1); STAGE_B(1, 1, t + 1);
    }
    __builtin_amdgcn_s_barrier();
    asm volatile("s_waitcnt lgkmcnt(0)" ::: "memory");
    __builtin_amdgcn_sched_barrier(0);
    __builtin_amdgcn_s_setprio(1);
#pragma unroll
    for (int mi = 0; mi < 4; ++mi)
#pragma unroll
      for (int ni = 0; ni < 2; ++ni) {
        acc[mi][ni] = MFMA_BF16(aL[mi][0], bL[ni][0], acc[mi][ni], 0, 0, 0);
        acc[mi][ni] = MFMA_BF16(aL[mi][1], bL[ni][1], acc[mi][ni], 0, 0, 0);
        acc[mi][ni + 2] = MFMA_BF16(aL[mi][0], bH[ni][0], acc[mi][ni + 2], 0, 0, 0);
        acc[mi][ni + 2] = MFMA_BF16(aL[mi][1], bH[ni][1], acc[mi][ni + 2], 0, 0, 0);
      }
    __builtin_amdgcn_s_setprio(0);
    __builtin_amdgcn_s_barrier();

    // ===== Phase 1: read aH(8); stage A0(t+2); vmcnt(2) (t+1 resident);
    //       BAR; lgkm0; MFMA Q2 (aH x bH) + Q3 (aH x bL) =====
    // WAR: A0(t+2) -> buf p A-half0; last reader aL(t) retired at P0(t) lgkm0,
    // one barrier before this stage. SAFE.
#pragma unroll
    for (int mi = 0; mi < 4; ++mi) {
      aH[mi][0] = *(const bf16x8_t*)(a0 + (mi + 4) * 2048 + c0);
      aH[mi][1] = *(const bf16x8_t*)(a0 + (mi + 4) * 2048 + c1);
    }
    if (t + 2 < NT) {
      STAGE_A(0, 0, t + 2); STAGE_A(0, 1, t + 2);
      // leave only A0(t+2) in flight -> A1/B0/B1(t+1) (issued P0(t)) and
      // A0(t+1) (issued P1(t-1)) have all landed
      asm volatile("s_waitcnt vmcnt(2)" ::: "memory");
    } else if (t + 1 < NT) {
      asm volatile("s_waitcnt vmcnt(0)" ::: "memory");  // tail drain
    }
    __builtin_amdgcn_s_barrier();
    asm volatile("s_waitcnt lgkmcnt(0)" ::: "memory");
    __builtin_amdgcn_sched_barrier(0);
    __builtin_amdgcn_s_setprio(1);
#pragma unroll
    for (int mi = 0; mi < 4; ++mi)
#pragma unroll
      for (int ni = 0; ni < 2; ++ni) {
        acc[mi + 4][ni + 2] = MFMA_BF16(aH[mi][0], bH[ni][0], acc[mi + 4][ni + 2], 0, 0, 0);
        acc[mi + 4][ni + 2] = MFMA_BF16(aH[mi][1], bH[ni][1], acc[mi + 4][ni + 2], 0, 0, 0);
        acc[mi + 4][ni] = MFMA_BF16(aH[mi][0], bL[ni][0], acc[mi + 4][ni], 0, 0, 0);
        acc[mi + 4][ni] = MFMA_BF16(aH[mi][1], bL[ni][1], acc[mi + 4][ni], 0, 0, 0);
      }
    __builtin_amdgcn_s_setprio(0);
    __builtin_amdgcn_s_barrier();
  }

  // ---- epilogue: C/D layout col=lane&15, row=(lane>>4)*4+reg ----
  const int row0 = m0 + wr * 128 + (lane >> 4) * 4;
  const int col0 = n0 + wc * 64 + lane15;
#pragma unroll
  for (int mi = 0; mi < 8; ++mi)
#pragma unroll
    for (int ni = 0; ni < 4; ++ni) {
#pragma unroll
      for (int k = 0; k < 4; ++k)
        out[(size_t)(row0 + mi * 16 + k) * N + col0 + ni * 16] = acc[mi][ni][k];
    }
#undef STAGE_A
#undef STAGE_B
}

// ------------------------------------------- fallback (no workspace): fused GEMM
__global__ __launch_bounds__(256) void gemm_fallback_kernel(const float* __restrict__ x,
                                                            const float* __restrict__ base,
                                                            const int* __restrict__ mask,
                                                            const float* __restrict__ coeffp,
                                                            float* __restrict__ out,
                                                            int M, int N, int K) {
  __shared__ __align__(16) __hip_bfloat16 As[128 * 32];
  __shared__ __align__(16) __hip_bfloat16 Bs[128 * 32];
  const float coeff = coeffp[0];
  const int ntn = N >> 7;
  const int tm = blockIdx.x / ntn, tn = blockIdx.x - tm * ntn;
  const int m0 = tm << 7, n0 = tn << 7;
  const int tid = threadIdx.x, lane = tid & 63, wave = tid >> 6;
  const int wr = wave >> 1, wc = wave & 1;

  f32x4_t acc[4][4];
  const f32x4_t zero = {0.0f, 0.0f, 0.0f, 0.0f};
#pragma unroll
  for (int i = 0; i < 4; ++i)
#pragma unroll
    for (int j = 0; j < 4; ++j) acc[i][j] = zero;

  const int arow = tid >> 1;
  const int acol = (tid & 1) * 16;
  const int bkk = tid & 31;
  const int bnb = (tid >> 5) * 16;
  const int arow_base = wr * 64 + (lane & 15);
  const int bcol_base = wc * 64 + (lane & 15);
  const int koff = (lane >> 4) * 8;

  for (int k0 = 0; k0 < K; k0 += 32) {
    __syncthreads();
    {
      const float* src = &x[(size_t)(m0 + arow) * K + k0 + acol];
      __hip_bfloat16 tmp[16];
#pragma unroll
      for (int j = 0; j < 16; ++j) tmp[j] = __float2bfloat16(src[j]);
      *(u16x8_t*)&As[arow * 32 + acol] = *(const u16x8_t*)&tmp[0];
      *(u16x8_t*)&As[arow * 32 + acol + 8] = *(const u16x8_t*)&tmp[8];
    }
    {
      const float* bsrc = &base[(size_t)(k0 + bkk) * N + n0 + bnb];
      const int* msrc = &mask[(size_t)(k0 + bkk) * N + n0 + bnb];
#pragma unroll
      for (int j = 0; j < 16; ++j) {
        float w = bsrc[j] + (msrc[j] ? coeff : -coeff);
        Bs[(bnb + j) * 32 + bkk] = __float2bfloat16(w);
      }
    }
    __syncthreads();

    bf16x8_t a[4], b[4];
#pragma unroll
    for (int mi = 0; mi < 4; ++mi)
      a[mi] = *(const bf16x8_t*)&As[(arow_base + mi * 16) * 32 + koff];
#pragma unroll
    for (int ni = 0; ni < 4; ++ni)
      b[ni] = *(const bf16x8_t*)&Bs[(bcol_base + ni * 16) * 32 + koff];
#pragma unroll
    for (int mi = 0; mi < 4; ++mi)
#pragma unroll
      for (int ni = 0; ni < 4; ++ni)
        acc[mi][ni] = MFMA_BF16(a[mi], b[ni], acc[mi][ni], 0, 0, 0);
  }

  const int row0 = m0 + wr * 64 + (lane >> 4) * 4;
  const int col0 = n0 + wc * 64 + (lane & 15);
#pragma unroll
  for (int mi = 0; mi < 4; ++mi)
#pragma unroll
    for (int ni = 0; ni < 4; ++ni) {
      int r = row0 + mi * 16;
      int c = col0 + ni * 16;
#pragma unroll
      for (int k = 0; k < 4; ++k) out[(size_t)(r + k) * N + c] = acc[mi][ni][k];
    }
}

// --------------------------------------------------------------------- launcher
extern "C" void kernel_launch(void* const* d_in, const int* in_sizes, int n_in,
                              void* d_out, int out_size, void* d_ws, size_t ws_size,
                              hipStream_t stream) {
  const int B = 4, S = 2048, DIN = 4096, DOUT = 4096;
  const int M = B * S;  // 8192
  const float* x = (const float*)d_in[0];
  const float* base = (const float*)d_in[1];
  const int* mask = (const int*)d_in[2];
  const float* coeff = (const float*)d_in[3];
  float* out = (float*)d_out;

  const size_t xb_bytes = (size_t)M * DIN * sizeof(__hip_bfloat16);
  const size_t wt_bytes = (size_t)DIN * DOUT * sizeof(__hip_bfloat16);

  if (ws_size >= xb_bytes + wt_bytes) {
    __hip_bfloat16* xb = (__hip_bfloat16*)d_ws;
    __hip_bfloat16* wt = (__hip_bfloat16*)((char*)d_ws + xb_bytes);
    cast_x_kernel<<<(M * DIN) / (256 * 8), 256, 0, stream>>>(x, xb);
    make_wt_kernel<<<dim3(DOUT / 32, DIN / 32), 256, 0, stream>>>(base, mask, coeff, wt, DIN, DOUT);
    const int n_tiles = (M / 256) * (DOUT / 256);  // 512
    gemm256_kernel<<<n_tiles, 512, 0, stream>>>(xb, wt, out, M, DOUT, DIN);
  } else {
    const int n_tiles = (M / 128) * (DOUT / 128);
    gemm_fallback_kernel<<<n_tiles, 256, 0, stream>>>(x, base, mask, coeff, out, M, DOUT, DIN);
  }
}